// Round 11
// baseline (1082.265 us; speedup 1.0000x reference)
//
#include <hip/hip_runtime.h>
#include <math.h>

#define B_SZ 512
#define S_SZ 512
#define E_NUM 8
#define F_DIM 20
#define BM 16          // pairs per group (full MFMA N-tile)
#define MAXBLK2 36     // 2 groups per block; ceil(71/2)

typedef __attribute__((ext_vector_type(8))) _Float16 f16x8;
typedef __attribute__((ext_vector_type(4))) float f32x4;
typedef __attribute__((ext_vector_type(4))) unsigned int u32x4;
#define MFMAH(a, b, c) __builtin_amdgcn_mfma_f32_16x16x32_f16(a, b, c, 0, 0, 0)

// pack two f32 -> f16 pair (RNE) in one dword
__device__ __forceinline__ unsigned pk16(float a, float b) {
  _Float16 ha = (_Float16)a, hb = (_Float16)b;
  unsigned short ua = __builtin_bit_cast(unsigned short, ha);
  unsigned short ub = __builtin_bit_cast(unsigned short, hb);
  return (unsigned)ua | ((unsigned)ub << 16);
}
__device__ __forceinline__ float ftanh(float x) {
  float e = __expf(x + x);  // +inf -> rcp(inf)=0 -> 1; -inf -> e=0 -> -1
  float r;
  asm("v_rcp_f32 %0, %1" : "=v"(r) : "v"(e + 1.0f));
  return fmaf(-2.0f, r, 1.0f);
}

// raw barrier: waits LDS ops only; global loads stay in flight
#define BAR() do {                                        \
  asm volatile("s_waitcnt lgkmcnt(0)" ::: "memory");      \
  __builtin_amdgcn_s_barrier();                           \
  asm volatile("" ::: "memory");                          \
} while (0)

// ---------------- Kernel 1: x_mean + logits ----------------
__global__ __launch_bounds__(512) void k_mean_logits(
    const float* __restrict__ x, const float* __restrict__ w_gate,
    float* __restrict__ logits) {
  __shared__ float sm[512];
  __shared__ float xm[128];
  int b = blockIdx.x;
  int t = threadIdx.x;
  int i = t & 127, s0 = t >> 7;
  const float* xb = x + (size_t)b * (S_SZ * 128);
  float acc = 0.f;
  for (int s = s0; s < S_SZ; s += 4) acc += xb[s * 128 + i];
  sm[t] = acc;
  __syncthreads();
  if (t < 128)
    xm[t] = (sm[t] + sm[t + 128] + sm[t + 256] + sm[t + 384]) * (1.0f / 512.0f);
  __syncthreads();
  if (t < E_NUM) {
    float acc2 = 0.f;
    for (int ii = 0; ii < 128; ii++) acc2 += xm[ii] * w_gate[ii * E_NUM + t];
    logits[b * E_NUM + t] = acc2;
  }
}

// ------- Kernel 2: top-2 gates + CV^2 loss + expert compaction -------
__global__ __launch_bounds__(512) void k_gate(
    const float* __restrict__ logits, float* __restrict__ sel_g,
    int* __restrict__ pair_b, int* __restrict__ pair_of,
    int* __restrict__ blk_e, int* __restrict__ blk_p0,
    int* __restrict__ blk_nr, int* __restrict__ nblk,
    float* __restrict__ loss_out) {
  __shared__ float gmat[512][8];
  __shared__ int cnt[8], base[8], pos[8];
  __shared__ float imps[8];
  int t = threadIdx.x;
  if (t < 8) { cnt[t] = 0; pos[t] = 0; }
  float lv[8];
#pragma unroll
  for (int e = 0; e < 8; e++) {
    lv[e] = logits[t * 8 + e];
    gmat[t][e] = 0.f;
  }
  __syncthreads();
  float v0 = -INFINITY, v1 = -INFINITY;
  int i0 = 0, i1 = 0;
#pragma unroll
  for (int e = 0; e < 8; e++) {
    float v = lv[e];
    if (v > v0) { v1 = v0; i1 = i0; v0 = v; i0 = e; }
    else if (v > v1) { v1 = v; i1 = e; }
  }
  float ex = expf(v1 - v0);
  float inv = 1.0f / (1.0f + ex);
  float g0 = inv, g1 = ex * inv;
  gmat[t][i0] = g0;
  gmat[t][i1] = g1;
  atomicAdd(&cnt[i0], 1);
  atomicAdd(&cnt[i1], 1);
  sel_g[t * 2] = g0;
  sel_g[t * 2 + 1] = g1;
  __syncthreads();
  if (t == 0) {
    int o = 0;
    for (int e = 0; e < 8; e++) { base[e] = o; o += cnt[e]; }
    int nb = 0;
    for (int e = 0; e < 8; e++)
      for (int off = 0; off < cnt[e]; off += BM) {
        blk_e[nb] = e;
        blk_p0[nb] = base[e] + off;
        blk_nr[nb] = min(BM, cnt[e] - off);
        nb++;
      }
    *nblk = nb;
  }
  if (t < 8) {
    float s = 0.f;
    for (int bb = 0; bb < 512; bb++) s += gmat[bb][t];
    imps[t] = s;
  }
  __syncthreads();
  {
    int r = atomicAdd(&pos[i0], 1);
    int p = base[i0] + r;
    pair_b[p] = t;
    pair_of[t * 2] = p;
  }
  {
    int r = atomicAdd(&pos[i1], 1);
    int p = base[i1] + r;
    pair_b[p] = t;
    pair_of[t * 2 + 1] = p;
  }
  if (t == 0) {
    float mi = 0.f, ml = 0.f;
#pragma unroll
    for (int e = 0; e < 8; e++) { mi += imps[e]; ml += (float)cnt[e]; }
    mi *= 0.125f; ml *= 0.125f;
    float vi = 0.f, vl = 0.f;
#pragma unroll
    for (int e = 0; e < 8; e++) {
      float di = imps[e] - mi; vi += di * di;
      float dl = (float)cnt[e] - ml; vl += dl * dl;
    }
    vi *= (1.0f / 7.0f);
    vl *= (1.0f / 7.0f);
    loss_out[0] = 0.01f * (vi / (mi * mi + 1e-10f) + vl / (ml * ml + 1e-10f));
  }
}

// ---- Kernel 3: two-group fused MoE-RNN, dual-role waves, all-f16-hi ----
// Block = 512 thr = 2 teams x 4 waves. Team t owns group 2*blk+t. Each wave:
// 2 M-tiles; produces P (x-proj from per-lane global x, 2 intervals ahead,
// P held in registers) and consumes (W_hh recurrence). Per SIMD: 2 waves of
// INDEPENDENT chains -> latency hiding. One barrier per interval. No setprio.
__global__ __launch_bounds__(512, 1) void k_moe(
    const float* __restrict__ x, const float* __restrict__ W_ih,
    const float* __restrict__ W_hh, const float* __restrict__ b_ih,
    const float* __restrict__ b_hh, const float* __restrict__ fc1_w,
    const float* __restrict__ fc1_b, const float* __restrict__ fc2_w,
    const float* __restrict__ fc2_b, const int* __restrict__ pair_b,
    const int* __restrict__ blk_e, const int* __restrict__ blk_p0,
    const int* __restrict__ blk_nr, const int* __restrict__ nblk,
    float* __restrict__ outp) {
  __shared__ unsigned short sH[2][2][2048];  // [team][parity] 16x128 f16
  __shared__ float sZ[2][BM * F_DIM];

  int nb = *nblk;
  if (blockIdx.x * 2 >= nb) return;  // whole block idle -> exit (uniform)
  int tid = threadIdx.x;
  int team = tid >> 8, tid4 = tid & 255;
  int grp = blockIdx.x * 2 + team;
  int valid = grp < nb;
  int e = valid ? blk_e[grp] : 0;
  int p0 = valid ? blk_p0[grp] : 0;
  int nr = valid ? blk_nr[grp] : 0;
  int lane = tid & 63, g = lane >> 4, ln = lane & 15;
  int w = (tid4 >> 6);  // wave-in-team 0..3; owns M-tiles 2w, 2w+1

  // ---- weights: f16 hi-only fragments straight from global ----
  f16x8 whh[2][4], wih[2][4];
#pragma unroll
  for (int m = 0; m < 2; m++) {
    int row = (2 * w + m) * 16 + ln;
    const float* bh = W_hh + (size_t)e * 16384 + row * 128 + g * 8;
    const float* bi = W_ih + (size_t)e * 16384 + row * 128 + g * 8;
#pragma unroll
    for (int ks = 0; ks < 4; ks++) {
      float4 a = *(const float4*)(bh + ks * 32);
      float4 b = *(const float4*)(bh + ks * 32 + 4);
      u32x4 t;
      t[0] = pk16(a.x, a.y); t[1] = pk16(a.z, a.w);
      t[2] = pk16(b.x, b.y); t[3] = pk16(b.z, b.w);
      whh[m][ks] = __builtin_bit_cast(f16x8, t);
      a = *(const float4*)(bi + ks * 32);
      b = *(const float4*)(bi + ks * 32 + 4);
      t[0] = pk16(a.x, a.y); t[1] = pk16(a.z, a.w);
      t[2] = pk16(b.x, b.y); t[3] = pk16(b.z, b.w);
      wih[m][ks] = __builtin_bit_cast(f16x8, t);
    }
  }
  f32x4 biasv[2];
#pragma unroll
  for (int m = 0; m < 2; m++)
#pragma unroll
    for (int r = 0; r < 4; r++) {
      int h = (2 * w + m) * 16 + g * 4 + r;
      biasv[m][r] = b_ih[e * 128 + h] + b_hh[e * 128 + h];
    }
  // zero all H slots (16 KB)
#pragma unroll
  for (int i = 0; i < 8; i++) ((unsigned int*)sH)[tid + i * 512] = 0;

  // per-lane x base: this lane's pair, k-slice g*8 floats (g*32 bytes)
  int bidx = pair_b[p0 + (ln < nr ? ln : 0)];
  const char* xlb = (const char*)x + (size_t)bidx * (S_SZ * 512) + g * 32;

  char* shb = (char*)sH + team * 8192;
  int swz = (ln & 7) << 4;
  int rdoff[4], wroff[2];
#pragma unroll
  for (int ks = 0; ks < 4; ks++) rdoff[ks] = (ln * 256 + ks * 64 + g * 16) ^ swz;
#pragma unroll
  for (int m = 0; m < 2; m++)
    wroff[m] = (ln * 256 + (2 * w + m) * 32 + g * 8) ^ swz;

  f32x4 Pa[2], Pb[2], Pc[2];
  float4 xA[8], xB[8];

#define LDX(XR, S)                                                           \
  _Pragma("unroll") for (int j = 0; j < 8; j++)                              \
      XR[j] = *(const float4*)(xlb + (size_t)(S) * 512 + (j >> 1) * 128 +    \
                               (j & 1) * 16);

#define CVTF(A, B, OUT)                                                      \
  do {                                                                       \
    u32x4 t_;                                                                \
    t_[0] = pk16(A.x, A.y); t_[1] = pk16(A.z, A.w);                          \
    t_[2] = pk16(B.x, B.y); t_[3] = pk16(B.z, B.w);                          \
    OUT = __builtin_bit_cast(f16x8, t_);                                     \
  } while (0)

#define PRDX(XR, PD)                                                         \
  do {                                                                       \
    f16x8 Xf0, Xf1, Xf2, Xf3;                                                \
    CVTF(XR[0], XR[1], Xf0);                                                 \
    CVTF(XR[2], XR[3], Xf1);                                                 \
    CVTF(XR[4], XR[5], Xf2);                                                 \
    CVTF(XR[6], XR[7], Xf3);                                                 \
    f32x4 q0 = biasv[0];                                                     \
    q0 = MFMAH(wih[0][0], Xf0, q0); q0 = MFMAH(wih[0][1], Xf1, q0);          \
    q0 = MFMAH(wih[0][2], Xf2, q0); q0 = MFMAH(wih[0][3], Xf3, q0);          \
    f32x4 q1 = biasv[1];                                                     \
    q1 = MFMAH(wih[1][0], Xf0, q1); q1 = MFMAH(wih[1][1], Xf1, q1);          \
    q1 = MFMAH(wih[1][2], Xf2, q1); q1 = MFMAH(wih[1][3], Xf3, q1);          \
    PD[0] = q0; PD[1] = q1;                                                  \
  } while (0)

// interval: H read (parity PAR), produce P[r+2] (PRDX from XR), reload XR
// with x[SLD]=x[r+4], recurrent chains from C=PU, tanh, H write, barrier.
#define STEP(PAR, PU, PD, XR, SLD, DOP, DOL)                                 \
  do {                                                                       \
    f16x8 Hf0 = *(const f16x8*)(shb + (PAR)*4096 + rdoff[0]);                \
    f16x8 Hf1 = *(const f16x8*)(shb + (PAR)*4096 + rdoff[1]);                \
    f16x8 Hf2 = *(const f16x8*)(shb + (PAR)*4096 + rdoff[2]);                \
    f16x8 Hf3 = *(const f16x8*)(shb + (PAR)*4096 + rdoff[3]);                \
    if (DOP) { PRDX(XR, PD); }                                               \
    if (DOL) { LDX(XR, SLD); }                                               \
    f32x4 pre0 = PU[0];                                                      \
    pre0 = MFMAH(whh[0][0], Hf0, pre0); pre0 = MFMAH(whh[0][1], Hf1, pre0);  \
    pre0 = MFMAH(whh[0][2], Hf2, pre0); pre0 = MFMAH(whh[0][3], Hf3, pre0);  \
    f32x4 pre1 = PU[1];                                                      \
    pre1 = MFMAH(whh[1][0], Hf0, pre1); pre1 = MFMAH(whh[1][1], Hf1, pre1);  \
    pre1 = MFMAH(whh[1][2], Hf2, pre1); pre1 = MFMAH(whh[1][3], Hf3, pre1);  \
    {                                                                        \
      float t0 = ftanh(pre0[0]), t1 = ftanh(pre0[1]);                        \
      float t2 = ftanh(pre0[2]), t3 = ftanh(pre0[3]);                        \
      uint2 hv = {pk16(t0, t1), pk16(t2, t3)};                               \
      *(uint2*)(shb + ((PAR) ^ 1) * 4096 + wroff[0]) = hv;                   \
    }                                                                        \
    {                                                                        \
      float t0 = ftanh(pre1[0]), t1 = ftanh(pre1[1]);                        \
      float t2 = ftanh(pre1[2]), t3 = ftanh(pre1[3]);                        \
      uint2 hv = {pk16(t0, t1), pk16(t2, t3)};                               \
      *(uint2*)(shb + ((PAR) ^ 1) * 4096 + wroff[1]) = hv;                   \
    }                                                                        \
    BAR();                                                                   \
  } while (0)

  // prologue: P[0], P[1]; x regs 2 intervals ahead
  LDX(xA, 0);
  LDX(xB, 1);
  PRDX(xA, Pa);  // P[0]
  LDX(xA, 2);
  PRDX(xB, Pb);  // P[1]
  LDX(xB, 3);
  BAR();  // H zeros + nothing else pending

  // interval r: PU=name(r%3), PD=name((r+2)%3), xset A(even)/B(odd),
  // H parity r&1, LDX step r+4.
#pragma unroll 1
  for (int r6 = 0; r6 < 504; r6 += 6) {
    STEP(0, Pa, Pc, xA, r6 + 4, 1, 1);
    STEP(1, Pb, Pa, xB, r6 + 5, 1, 1);
    STEP(0, Pc, Pb, xA, r6 + 6, 1, 1);
    STEP(1, Pa, Pc, xB, r6 + 7, 1, 1);
    STEP(0, Pb, Pa, xA, r6 + 8, 1, 1);
    STEP(1, Pc, Pb, xB, r6 + 9, 1, 1);
  }
  STEP(0, Pa, Pc, xA, 508, 1, 1);  // r=504
  STEP(1, Pb, Pa, xB, 509, 1, 1);  // r=505
  STEP(0, Pc, Pb, xA, 510, 1, 1);  // r=506
  STEP(1, Pa, Pc, xB, 511, 1, 1);  // r=507
  STEP(0, Pb, Pa, xA, 0, 1, 0);    // r=508 -> P[510]
  STEP(1, Pc, Pb, xB, 0, 1, 0);    // r=509 -> P[511]
  STEP(0, Pa, Pc, xA, 0, 0, 0);    // r=510
  STEP(1, Pb, Pa, xB, 0, 0, 0);    // r=511; h_512 -> parity 0
#undef STEP
#undef PRDX
#undef CVTF
#undef LDX

  // ---- MLP head: h_512 (f16) in this team's parity-0 slot ----
  {
    int p = tid4 >> 4, q = tid4 & 15;
#pragma unroll
    for (int pass = 0; pass < 2; pass++) {
      int f = q + pass * 16;
      if (f < F_DIM) {
        float acc = fc1_b[e * F_DIM + f];
        const float* w1 = fc1_w + (size_t)e * (F_DIM * 128) + f * 128;
        for (int k = 0; k < 128; k++) {
          int off = (p * 256 + k * 2) ^ ((p & 7) << 4);
          float h = (float)(*(const _Float16*)(shb + off));
          acc = fmaf(h, w1[k], acc);
        }
        sZ[team][p * F_DIM + f] = ftanh(acc);
      }
    }
  }
  __syncthreads();
  if (tid4 < BM) {
    float acc = fc2_b[e];
#pragma unroll
    for (int f = 0; f < F_DIM; f++)
      acc += sZ[team][tid4 * F_DIM + f] * fc2_w[e * F_DIM + f];
    if (tid4 < nr) outp[p0 + tid4] = acc;
  }
}

// ---------------- Kernel 4: weighted combine ----------------
__global__ void k_combine(const float* __restrict__ sel_g,
                          const int* __restrict__ pair_of,
                          const float* __restrict__ outp,
                          float* __restrict__ y) {
  int b = blockIdx.x * blockDim.x + threadIdx.x;
  if (b < B_SZ)
    y[b] = sel_g[2 * b] * outp[pair_of[2 * b]] +
           sel_g[2 * b + 1] * outp[pair_of[2 * b + 1]];
}

extern "C" void kernel_launch(void* const* d_in, const int* in_sizes, int n_in,
                              void* d_out, int out_size, void* d_ws,
                              size_t ws_size, hipStream_t stream) {
  (void)in_sizes; (void)n_in; (void)out_size; (void)ws_size;
  const float* x      = (const float*)d_in[0];
  const float* w_gate = (const float*)d_in[1];
  const float* W_ih   = (const float*)d_in[2];
  const float* W_hh   = (const float*)d_in[3];
  const float* b_ih   = (const float*)d_in[4];
  const float* b_hh   = (const float*)d_in[5];
  const float* fc1_w  = (const float*)d_in[6];
  const float* fc1_b  = (const float*)d_in[7];
  const float* fc2_w  = (const float*)d_in[8];
  const float* fc2_b  = (const float*)d_in[9];
  float* out = (float*)d_out;  // [0..511] = y, [512] = loss

  float* logits = (float*)d_ws;            // 4096 f32
  float* sel_g  = logits + 4096;           // 1024 f32
  int*   pair_b = (int*)(sel_g + 1024);    // 1024 i32
  int*   pair_of= pair_b + 1024;           // 1024 i32
  int*   blk_e  = pair_of + 1024;          // 128 i32
  int*   blk_p0 = blk_e + 128;             // 128 i32
  int*   blk_nr = blk_p0 + 128;            // 128 i32
  int*   nblk   = blk_nr + 128;            // 8 i32
  float* outp   = (float*)(nblk + 8);      // 1024 f32

  k_mean_logits<<<B_SZ, 512, 0, stream>>>(x, w_gate, logits);
  k_gate<<<1, 512, 0, stream>>>(logits, sel_g, pair_b, pair_of, blk_e, blk_p0,
                                blk_nr, nblk, out + 512);
  k_moe<<<MAXBLK2, 512, 0, stream>>>(x, W_ih, W_hh, b_ih, b_hh, fc1_w, fc1_b,
                                     fc2_w, fc2_b, pair_b, blk_e, blk_p0,
                                     blk_nr, nblk, outp);
  k_combine<<<2, 256, 0, stream>>>(sel_g, pair_of, outp, out);
}

// Round 13
// 314.325 us; speedup vs baseline: 3.4431x; 3.4431x over previous
//
#include <hip/hip_runtime.h>
#include <math.h>

#define B_SZ 512
#define S_SZ 512
#define E_NUM 8
#define F_DIM 20
#define BM 16          // pairs per RNN block (full MFMA N-tile)
#define MAXBLK 71      // max sum_e ceil(cnt_e/16) = 71

typedef __attribute__((ext_vector_type(8))) _Float16 f16x8;
typedef __attribute__((ext_vector_type(4))) float f32x4;
typedef __attribute__((ext_vector_type(4))) unsigned int u32x4;
#define MFMAH(a, b, c) __builtin_amdgcn_mfma_f32_16x16x32_f16(a, b, c, 0, 0, 0)

// pack two f32 -> f16 pair (RNE) in one dword
__device__ __forceinline__ unsigned pk16(float a, float b) {
  _Float16 ha = (_Float16)a, hb = (_Float16)b;
  unsigned short ua = __builtin_bit_cast(unsigned short, ha);
  unsigned short ub = __builtin_bit_cast(unsigned short, hb);
  return (unsigned)ua | ((unsigned)ub << 16);
}
__device__ __forceinline__ float ftanh(float x) {
  float e = __expf(x + x);  // +inf -> rcp(inf)=0 -> 1; -inf -> e=0 -> -1
  float r;
  asm("v_rcp_f32 %0, %1" : "=v"(r) : "v"(e + 1.0f));
  return fmaf(-2.0f, r, 1.0f);
}

// raw barrier: waits LDS ops only; global loads stay in flight
#define BAR() do {                                        \
  asm volatile("s_waitcnt lgkmcnt(0)" ::: "memory");      \
  __builtin_amdgcn_s_barrier();                           \
  asm volatile("" ::: "memory");                          \
} while (0)

// ---------------- Kernel 1: x_mean + logits ----------------
__global__ __launch_bounds__(512) void k_mean_logits(
    const float* __restrict__ x, const float* __restrict__ w_gate,
    float* __restrict__ logits) {
  __shared__ float sm[512];
  __shared__ float xm[128];
  int b = blockIdx.x;
  int t = threadIdx.x;
  int i = t & 127, s0 = t >> 7;
  const float* xb = x + (size_t)b * (S_SZ * 128);
  float acc = 0.f;
  for (int s = s0; s < S_SZ; s += 4) acc += xb[s * 128 + i];
  sm[t] = acc;
  __syncthreads();
  if (t < 128)
    xm[t] = (sm[t] + sm[t + 128] + sm[t + 256] + sm[t + 384]) * (1.0f / 512.0f);
  __syncthreads();
  if (t < E_NUM) {
    float acc2 = 0.f;
    for (int ii = 0; ii < 128; ii++) acc2 += xm[ii] * w_gate[ii * E_NUM + t];
    logits[b * E_NUM + t] = acc2;
  }
}

// ------- Kernel 2: top-2 gates + CV^2 loss + expert compaction -------
__global__ __launch_bounds__(512) void k_gate(
    const float* __restrict__ logits, float* __restrict__ sel_g,
    int* __restrict__ pair_b, int* __restrict__ pair_of,
    int* __restrict__ blk_e, int* __restrict__ blk_p0,
    int* __restrict__ blk_nr, int* __restrict__ nblk,
    float* __restrict__ loss_out) {
  __shared__ float gmat[512][8];
  __shared__ int cnt[8], base[8], pos[8];
  __shared__ float imps[8];
  int t = threadIdx.x;
  if (t < 8) { cnt[t] = 0; pos[t] = 0; }
  float lv[8];
#pragma unroll
  for (int e = 0; e < 8; e++) {
    lv[e] = logits[t * 8 + e];
    gmat[t][e] = 0.f;
  }
  __syncthreads();
  float v0 = -INFINITY, v1 = -INFINITY;
  int i0 = 0, i1 = 0;
#pragma unroll
  for (int e = 0; e < 8; e++) {
    float v = lv[e];
    if (v > v0) { v1 = v0; i1 = i0; v0 = v; i0 = e; }
    else if (v > v1) { v1 = v; i1 = e; }
  }
  float ex = expf(v1 - v0);
  float inv = 1.0f / (1.0f + ex);
  float g0 = inv, g1 = ex * inv;
  gmat[t][i0] = g0;
  gmat[t][i1] = g1;
  atomicAdd(&cnt[i0], 1);
  atomicAdd(&cnt[i1], 1);
  sel_g[t * 2] = g0;
  sel_g[t * 2 + 1] = g1;
  __syncthreads();
  if (t == 0) {
    int o = 0;
    for (int e = 0; e < 8; e++) { base[e] = o; o += cnt[e]; }
    int nb = 0;
    for (int e = 0; e < 8; e++)
      for (int off = 0; off < cnt[e]; off += BM) {
        blk_e[nb] = e;
        blk_p0[nb] = base[e] + off;
        blk_nr[nb] = min(BM, cnt[e] - off);
        nb++;
      }
    *nblk = nb;
  }
  if (t < 8) {
    float s = 0.f;
    for (int bb = 0; bb < 512; bb++) s += gmat[bb][t];
    imps[t] = s;
  }
  __syncthreads();
  {
    int r = atomicAdd(&pos[i0], 1);
    int p = base[i0] + r;
    pair_b[p] = t;
    pair_of[t * 2] = p;
  }
  {
    int r = atomicAdd(&pos[i1], 1);
    int p = base[i1] + r;
    pair_b[p] = t;
    pair_of[t * 2 + 1] = p;
  }
  if (t == 0) {
    float mi = 0.f, ml = 0.f;
#pragma unroll
    for (int e = 0; e < 8; e++) { mi += imps[e]; ml += (float)cnt[e]; }
    mi *= 0.125f; ml *= 0.125f;
    float vi = 0.f, vl = 0.f;
#pragma unroll
    for (int e = 0; e < 8; e++) {
      float di = imps[e] - mi; vi += di * di;
      float dl = (float)cnt[e] - ml; vl += dl * dl;
    }
    vi *= (1.0f / 7.0f);
    vl *= (1.0f / 7.0f);
    loss_out[0] = 0.01f * (vi / (mi * mi + 1e-10f) + vl / (ml * ml + 1e-10f));
  }
}

// ---- Kernel 3: fused producer/consumer MoE-RNN (r8 structure, f16-hi) ----
// waves 0-3: producers — stage x (f16) into 4-slot LDS ring, compute
//   P[s] = W_ih·x_s + biases (hi-only f16 W) into 2-slot LDS P ring.
// waves 4-7: consumers — h_{s+1} = tanh(P[s] + W_hh·h_s) (hi-only f16 W_hh,
//   f16 H ping-pong; two independent 2-deep MFMA chains + add).
// EXACTLY one raw barrier per role per round (ledger: 514 == 514).
__global__ __launch_bounds__(512, 2) void k_moe(
    const float* __restrict__ x, const float* __restrict__ W_ih,
    const float* __restrict__ W_hh, const float* __restrict__ b_ih,
    const float* __restrict__ b_hh, const float* __restrict__ fc1_w,
    const float* __restrict__ fc1_b, const float* __restrict__ fc2_w,
    const float* __restrict__ fc2_b, const int* __restrict__ pair_b,
    const int* __restrict__ blk_e, const int* __restrict__ blk_p0,
    const int* __restrict__ blk_nr, const int* __restrict__ nblk,
    float* __restrict__ outp) {
  __shared__ unsigned short sX[4][2048];  // f16 X ring, 4 x 4KB
  __shared__ float sP[2][2048];           // f32 P ring, 2 x 8KB
  __shared__ unsigned short sH[2][2048];  // f16 H ping-pong, 2 x 4KB
  __shared__ float sZ[BM * F_DIM];

  int blk = blockIdx.x;
  if (blk >= *nblk) return;
  int e = blk_e[blk], p0 = blk_p0[blk], nr = blk_nr[blk];
  int tid = threadIdx.x;
  int lane = tid & 63, g = lane >> 4, ln = lane & 15;
  int wv = tid >> 6;

  char* sxb = (char*)&sX[0][0];
  char* spb = (char*)&sP[0][0];
  char* shb = (char*)&sH[0][0];

  // zero H slot 0 (4KB)
  ((unsigned int*)shb)[tid] = 0;
  ((unsigned int*)shb)[tid + 512] = 0;

  // fragment-read offsets (16 rows x 128 f16, XOR swizzle)
  int swz = (ln & 7) << 4;
  int rdoff[4];
#pragma unroll
  for (int ks = 0; ks < 4; ks++) rdoff[ks] = (ln * 256 + ks * 64 + g * 16) ^ swz;

  const f32x4 Z4 = {0.f, 0.f, 0.f, 0.f};

  if (wv < 4) {
    // ================== PRODUCER (M-tiles 2wv, 2wv+1) ==================
    int w = wv;
    f16x8 wih[2][4];
#pragma unroll
    for (int m = 0; m < 2; m++) {
      int row = (2 * w + m) * 16 + ln;
      const float* bi = W_ih + (size_t)e * 16384 + row * 128 + g * 8;
#pragma unroll
      for (int ks = 0; ks < 4; ks++) {
        float4 a = *(const float4*)(bi + ks * 32);
        float4 b = *(const float4*)(bi + ks * 32 + 4);
        u32x4 t;
        t[0] = pk16(a.x, a.y); t[1] = pk16(a.z, a.w);
        t[2] = pk16(b.x, b.y); t[3] = pk16(b.z, b.w);
        wih[m][ks] = __builtin_bit_cast(f16x8, t);
      }
    }
    f32x4 biasv[2];
#pragma unroll
    for (int m = 0; m < 2; m++)
#pragma unroll
      for (int r = 0; r < 4; r++) {
        int h = (2 * w + m) * 16 + g * 4 + r;
        biasv[m][r] = b_ih[e * 128 + h] + b_hh[e * 128 + h];
      }
    int pwoff[2];
#pragma unroll
    for (int m = 0; m < 2; m++)
      pwoff[m] = (2 * w + m) * 1024 + g * 256 + ln * 16;

    // staging: lane handles row 4w+(lane>>4), elems k0..k0+7
    int srow = 4 * w + (lane >> 4);
    int k0 = (lane & 15) * 8;
    int sb = pair_b[p0 + (srow < nr ? srow : 0)];
    const char* xsrc = (const char*)x + (size_t)sb * (S_SZ * 512) + k0 * 4;
    int stoff = (srow * 256 + k0 * 2) ^ ((srow & 7) << 4);

    float4 xa0, xa1, xb0, xb1;

#define LDX(B0, B1, STEP)                                                    \
  do {                                                                       \
    B0 = *(const float4*)(xsrc + (size_t)(STEP) * 512);                      \
    B1 = *(const float4*)(xsrc + (size_t)(STEP) * 512 + 16);                 \
  } while (0)

#define STG(WS, B0, B1)                                                      \
  do {                                                                       \
    float v[8] = {B0.x, B0.y, B0.z, B0.w, B1.x, B1.y, B1.z, B1.w};           \
    f16x8 hx;                                                                \
    _Pragma("unroll") for (int j = 0; j < 8; j++) hx[j] = (_Float16)v[j];    \
    *(f16x8*)(sxb + ((WS) << 12) + stoff) = hx;                              \
  } while (0)

#define PRD(XS, PS)                                                          \
  do {                                                                       \
    f16x8 Xf0 = *(const f16x8*)(sxb + ((XS) << 12) + rdoff[0]);              \
    f16x8 Xf1 = *(const f16x8*)(sxb + ((XS) << 12) + rdoff[1]);              \
    f16x8 Xf2 = *(const f16x8*)(sxb + ((XS) << 12) + rdoff[2]);              \
    f16x8 Xf3 = *(const f16x8*)(sxb + ((XS) << 12) + rdoff[3]);              \
    _Pragma("unroll") for (int m = 0; m < 2; m++) {                          \
      f32x4 pA = biasv[m];                                                   \
      pA = MFMAH(wih[m][0], Xf0, pA);                                        \
      pA = MFMAH(wih[m][1], Xf1, pA);                                        \
      pA = MFMAH(wih[m][2], Xf2, pA);                                        \
      pA = MFMAH(wih[m][3], Xf3, pA);                                        \
      *(f32x4*)(spb + ((PS) << 13) + pwoff[m]) = pA;                         \
    }                                                                        \
  } while (0)

    // prologue
    LDX(xa0, xa1, 0);
    LDX(xb0, xb1, 1);
    STG(0, xa0, xa1);
    STG(1, xb0, xb1);
    LDX(xa0, xa1, 2);
    LDX(xb0, xb1, 3);
    BAR();  // #1: X0,X1,H0 visible
    PRD(0, 0);           // P[0]
    STG(2, xa0, xa1);    // X[2]
    LDX(xa0, xa1, 4);
    BAR();  // #2: P0,X2 visible

    // main rounds r = 0..503
#pragma unroll 1
    for (int r4 = 0; r4 < 504; r4 += 4) {
      PRD(1, 1); STG(3, xb0, xb1); LDX(xb0, xb1, r4 + 5); BAR();
      PRD(2, 0); STG(0, xa0, xa1); LDX(xa0, xa1, r4 + 6); BAR();
      PRD(3, 1); STG(1, xb0, xb1); LDX(xb0, xb1, r4 + 7); BAR();
      PRD(0, 0); STG(2, xa0, xa1); LDX(xa0, xa1, r4 + 8); BAR();
    }
    // tail rounds r = 504..511
    PRD(1, 1); STG(3, xb0, xb1); LDX(xb0, xb1, 509); BAR();  // 504
    PRD(2, 0); STG(0, xa0, xa1); LDX(xa0, xa1, 510); BAR();  // 505
    PRD(3, 1); STG(1, xb0, xb1); LDX(xb0, xb1, 511); BAR();  // 506
    PRD(0, 0); STG(2, xa0, xa1); BAR();                      // 507
    PRD(1, 1); STG(3, xb0, xb1); BAR();                      // 508
    PRD(2, 0); BAR();                                        // 509
    PRD(3, 1); BAR();                                        // 510 -> P[511]
    BAR();                                                   // 511
#undef PRD
#undef STG
#undef LDX
  } else {
    // ================== CONSUMER (M-tiles 2w2, 2w2+1) ==================
    int w2 = wv - 4;
    f16x8 wh[2][4];
#pragma unroll
    for (int m = 0; m < 2; m++) {
      int row = (2 * w2 + m) * 16 + ln;
      const float* bh = W_hh + (size_t)e * 16384 + row * 128 + g * 8;
#pragma unroll
      for (int ks = 0; ks < 4; ks++) {
        float4 a = *(const float4*)(bh + ks * 32);
        float4 b = *(const float4*)(bh + ks * 32 + 4);
        u32x4 t;
        t[0] = pk16(a.x, a.y); t[1] = pk16(a.z, a.w);
        t[2] = pk16(b.x, b.y); t[3] = pk16(b.z, b.w);
        wh[m][ks] = __builtin_bit_cast(f16x8, t);
      }
    }
    int proff[2], wroff[2];
#pragma unroll
    for (int m = 0; m < 2; m++) {
      proff[m] = (2 * w2 + m) * 1024 + g * 256 + ln * 16;
      wroff[m] = (ln * 256 + (2 * w2 + m) * 32 + g * 8) ^ swz;
    }

// one BAR per CRD (inside macro) — do NOT add more in the loop
#define CRD(RS)                                                              \
  do {                                                                       \
    f16x8 Hf0 = *(const f16x8*)(shb + (RS)*4096 + rdoff[0]);                 \
    f16x8 Hf1 = *(const f16x8*)(shb + (RS)*4096 + rdoff[1]);                 \
    f16x8 Hf2 = *(const f16x8*)(shb + (RS)*4096 + rdoff[2]);                 \
    f16x8 Hf3 = *(const f16x8*)(shb + (RS)*4096 + rdoff[3]);                 \
    f32x4 pP0 = *(const f32x4*)(spb + ((RS) << 13) + proff[0]);              \
    f32x4 pP1 = *(const f32x4*)(spb + ((RS) << 13) + proff[1]);              \
    f32x4 a0 = MFMAH(wh[0][0], Hf0, pP0); a0 = MFMAH(wh[0][1], Hf1, a0);     \
    f32x4 b0 = MFMAH(wh[0][2], Hf2, Z4);  b0 = MFMAH(wh[0][3], Hf3, b0);     \
    f32x4 a1 = MFMAH(wh[1][0], Hf0, pP1); a1 = MFMAH(wh[1][1], Hf1, a1);     \
    f32x4 b1 = MFMAH(wh[1][2], Hf2, Z4);  b1 = MFMAH(wh[1][3], Hf3, b1);     \
    {                                                                        \
      float t0 = ftanh(a0[0] + b0[0]), t1 = ftanh(a0[1] + b0[1]);            \
      float t2 = ftanh(a0[2] + b0[2]), t3 = ftanh(a0[3] + b0[3]);            \
      uint2 hv = {pk16(t0, t1), pk16(t2, t3)};                               \
      *(uint2*)(shb + ((RS) ^ 1) * 4096 + wroff[0]) = hv;                    \
    }                                                                        \
    {                                                                        \
      float t0 = ftanh(a1[0] + b1[0]), t1 = ftanh(a1[1] + b1[1]);            \
      float t2 = ftanh(a1[2] + b1[2]), t3 = ftanh(a1[3] + b1[3]);            \
      uint2 hv = {pk16(t0, t1), pk16(t2, t3)};                               \
      *(uint2*)(shb + ((RS) ^ 1) * 4096 + wroff[1]) = hv;                    \
    }                                                                        \
    BAR();                                                                   \
  } while (0)

    BAR();  // #1
    BAR();  // #2
#pragma unroll 1
    for (int it = 0; it < 128; it++) {
      CRD(0);
      CRD(1);
      CRD(0);
      CRD(1);
    }
#undef CRD
  }

  // ---- MLP head: h_512 (f16) in sH slot 0 ----
  {
    int p = tid >> 5, q = tid & 31;
    if (q < F_DIM) {
      float acc = fc1_b[e * F_DIM + q];
      const float* w1 = fc1_w + (size_t)e * (F_DIM * 128) + q * 128;
      for (int k = 0; k < 128; k++) {
        int off = (p * 256 + k * 2) ^ ((p & 7) << 4);
        float h = (float)(*(const _Float16*)(shb + off));
        acc = fmaf(h, w1[k], acc);
      }
      sZ[p * F_DIM + q] = ftanh(acc);
    }
  }
  __syncthreads();
  if (tid < BM) {
    float acc = fc2_b[e];
#pragma unroll
    for (int f = 0; f < F_DIM; f++)
      acc += sZ[tid * F_DIM + f] * fc2_w[e * F_DIM + f];
    if (tid < nr) outp[p0 + tid] = acc;
  }
}

// ---------------- Kernel 4: weighted combine ----------------
__global__ void k_combine(const float* __restrict__ sel_g,
                          const int* __restrict__ pair_of,
                          const float* __restrict__ outp,
                          float* __restrict__ y) {
  int b = blockIdx.x * blockDim.x + threadIdx.x;
  if (b < B_SZ)
    y[b] = sel_g[2 * b] * outp[pair_of[2 * b]] +
           sel_g[2 * b + 1] * outp[pair_of[2 * b + 1]];
}

extern "C" void kernel_launch(void* const* d_in, const int* in_sizes, int n_in,
                              void* d_out, int out_size, void* d_ws,
                              size_t ws_size, hipStream_t stream) {
  (void)in_sizes; (void)n_in; (void)out_size; (void)ws_size;
  const float* x      = (const float*)d_in[0];
  const float* w_gate = (const float*)d_in[1];
  const float* W_ih   = (const float*)d_in[2];
  const float* W_hh   = (const float*)d_in[3];
  const float* b_ih   = (const float*)d_in[4];
  const float* b_hh   = (const float*)d_in[5];
  const float* fc1_w  = (const float*)d_in[6];
  const float* fc1_b  = (const float*)d_in[7];
  const float* fc2_w  = (const float*)d_in[8];
  const float* fc2_b  = (const float*)d_in[9];
  float* out = (float*)d_out;  // [0..511] = y, [512] = loss

  float* logits = (float*)d_ws;            // 4096 f32
  float* sel_g  = logits + 4096;           // 1024 f32
  int*   pair_b = (int*)(sel_g + 1024);    // 1024 i32
  int*   pair_of= pair_b + 1024;           // 1024 i32
  int*   blk_e  = pair_of + 1024;          // 128 i32
  int*   blk_p0 = blk_e + 128;             // 128 i32
  int*   blk_nr = blk_p0 + 128;            // 128 i32
  int*   nblk   = blk_nr + 128;            // 8 i32
  float* outp   = (float*)(nblk + 8);      // 1024 f32

  k_mean_logits<<<B_SZ, 512, 0, stream>>>(x, w_gate, logits);
  k_gate<<<1, 512, 0, stream>>>(logits, sel_g, pair_b, pair_of, blk_e, blk_p0,
                                blk_nr, nblk, out + 512);
  k_moe<<<MAXBLK, 512, 0, stream>>>(x, W_ih, W_hh, b_ih, b_hh, fc1_w, fc1_b,
                                    fc2_w, fc2_b, pair_b, blk_e, blk_p0,
                                    blk_nr, nblk, outp);
  k_combine<<<2, 256, 0, stream>>>(sel_g, pair_of, outp, out);
}